// Round 1
// baseline (565.644 us; speedup 1.0000x reference)
//
#include <hip/hip_runtime.h>
#include <math.h>
#include <stdint.h>

// Problem: M=131072 rows, N=4000 verts (padded to 4096), D=16.
#define M_ROWS   131072
#define N_VERTS  4000
#define N_PAD    4096
#define D_DIM    16
#define N_TILES  (N_PAD / 32)          // 128 n-tiles of 32 verts
#define TILE_B   3072                  // per tile: yh 1KB | yl 1KB | ysf 1KB
#define CHUNK_T  8                     // tiles per LDS chunk
#define CHUNK_B  (CHUNK_T * TILE_B)    // 24576 B per chunk
#define N_CHUNKS (N_TILES / CHUNK_T)   // 16

// Scores are biased +128 so they are provably positive (score >= -||x||^2 and
// ||x||^2 < 128 for chi^2_16 data at astronomical confidence) -> positive-float
// bit pattern is monotone as u32 -> min_u32 does argmin via packed keys.
#define SCORE_BIAS 128.0f
// key = (score_bits & ~0xFF) | tile (tile 0..127 fits in 8 bits).
// Error budget: 8-bit mantissa truncation <= 7.8e-3 (score<256 for near-best),
// split-bf16 arithmetic ~1e-3, dropped al*yl cross term <= 4.9e-4,
// ys carried as bf16 hi+lo pair <= 7.3e-4.  TIE_EPS = 0.03 >= 2x total.
#define TIE_EPS 0.03f

// d_ws layout (bytes):
//   [0      .. 393216)  yfrag : N_TILES x 3072 B, fragment-ordered 32x32 data
//   [393216 .. 393220)  cnt
//   [393280 .. ...   )  list  : ambiguous row indices
#define WS_YFRAG_OFF 0
#define WS_CNT_OFF   393216
#define WS_LIST_OFF  393280

typedef float f32x16 __attribute__((ext_vector_type(16)));
typedef short s16x8  __attribute__((ext_vector_type(8)));

__device__ __forceinline__ unsigned short f32_to_bf16_rne(float f) {
    unsigned int u = __float_as_uint(f);
    u = (u + 0x7fffu + ((u >> 16) & 1u)) >> 16;
    return (unsigned short)u;
}
__device__ __forceinline__ float bf16_to_f32(unsigned short h) {
    return __uint_as_float(((unsigned int)h) << 16);
}
__device__ __forceinline__ uint32_t umin32(uint32_t a, uint32_t b) { return a < b ? a : b; }
__device__ __forceinline__ uint32_t umax32(uint32_t a, uint32_t b) { return a > b ? a : b; }

// ---------------------------------------------------------------------------
// Kernel 1: pack Y into 32x32-MFMA fragment order.
// B-operand layout for mfma_f32_32x32x16_bf16 (analog of the HW-verified
// 16x16x32 layout used before): B[n = lane&31][k = (lane>>5)*8 + j].
// Per tile T (32 verts): yh frag (64 lanes x 16B), yl frag, ysf frag.
// ysf holds (bias+||y||^2) as a bf16 hi/lo pair in k-slots 0,1 (lanes<32),
// consumed by an extra MFMA against a "ones" A-fragment -> acc init via MFMA.
// One thread per (tile, lane) = 8192 threads.
// ---------------------------------------------------------------------------
__global__ void pack_y_kernel(const float* __restrict__ verts,
                              char* __restrict__ yfrag,
                              int* __restrict__ cnt) {
    const int tid = blockIdx.x * blockDim.x + threadIdx.x;   // 0..8191
    if (tid == 0) *cnt = 0;

    const int T   = tid >> 6;
    const int l   = tid & 63;
    const int col = l & 31;
    const int h   = l >> 5;
    const int n   = T * 32 + col;
    const int d0  = h * 8;

    float v[8];
    if (n < N_VERTS) {
        const float* y = verts + (size_t)n * D_DIM + d0;
#pragma unroll
        for (int j = 0; j < 8; ++j) v[j] = y[j];
    } else {
#pragma unroll
        for (int j = 0; j < 8; ++j) v[j] = 0.f;
    }
    s16x8 fh, fl;
#pragma unroll
    for (int j = 0; j < 8; ++j) {
        const unsigned short hh = f32_to_bf16_rne(v[j]);
        fh[j] = (short)hh;
        fl[j] = (short)f32_to_bf16_rne(v[j] - bf16_to_f32(hh));
    }
    char* tb = yfrag + (size_t)T * TILE_B + (size_t)l * 16;
    *(s16x8*)(tb)        = fh;
    *(s16x8*)(tb + 1024) = fl;

    // ysf: k-slots 0,1 (lanes < 32) hold bf16 hi/lo of bias+||y||^2.
    s16x8 fy;
#pragma unroll
    for (int j = 0; j < 8; ++j) fy[j] = 0;
    if (h == 0) {
        float ys;
        if (n < N_VERTS) {
            ys = SCORE_BIAS;
            const float* y = verts + (size_t)n * D_DIM;
#pragma unroll
            for (int d = 0; d < D_DIM; ++d) ys = fmaf(y[d], y[d], ys);
        } else {
            ys = 1e30f;   // pad cols never win
        }
        const unsigned short ysh = f32_to_bf16_rne(ys);
        fy[0] = (short)ysh;
        fy[1] = (short)f32_to_bf16_rne(ys - bf16_to_f32(ysh));
    }
    *(s16x8*)(tb + 2048) = fy;
}

// ---------------------------------------------------------------------------
// Kernel 2 (MFMA screen, 32x32x16): 512 thr = 8 waves, wave = 32 rows x all n.
// Per tile: acc = ones*ysf + ah*yh + al*yh + ah*yl  (4 chained MFMAs,
// persistent zero16 C-operand, no per-tile acc-init movs).
// Key = (bits & ~0xFF) | tile -> min_u32 tracks best+argmin, max/min second.
// Double-buffered 24KB LDS chunks, ONE barrier per chunk (reg-prefetch).
// Grid = 512 blocks: all co-resident at 2 blocks/CU (48KB LDS) -> zero tail.
// ---------------------------------------------------------------------------
__global__ __launch_bounds__(512, 4) void mfma_screen_kernel(
    const float* __restrict__ x_all,    // (M,16)
    const float* __restrict__ colors,   // (N,3)
    const char* __restrict__ yfrag,     // N_TILES x 3072 B
    float* __restrict__ out,            // (M,3)
    int* __restrict__ cnt,
    int* __restrict__ list,
    int list_cap)
{
    __shared__ __align__(16) char s_buf[2 * CHUNK_B];   // 48 KB (reused for reduce)

    const int tid  = threadIdx.x;
    const int wave = tid >> 6;
    const int lane = tid & 63;
    const int col  = lane & 31;          // A row / B col / C-D col
    const int h    = lane >> 5;          // k-half select
    const int rowBase = blockIdx.x * 256 + wave * 32;

    // --- A fragments (built once). Lane supplies A[m=col][k=h*8+j].
    const float* xr = x_all + (size_t)(rowBase + col) * D_DIM + h * 8;
    const float4 xa = *(const float4*)xr;
    const float4 xb = *(const float4*)(xr + 4);
    const float xv[8] = {xa.x, xa.y, xa.z, xa.w, xb.x, xb.y, xb.z, xb.w};
    s16x8 a1, a2;
#pragma unroll
    for (int j = 0; j < 8; ++j) {
        const float a = -2.0f * xv[j];
        const unsigned short hh = f32_to_bf16_rne(a);
        a1[j] = (short)hh;
        a2[j] = (short)f32_to_bf16_rne(a - bf16_to_f32(hh));
    }
    // ones-A for the ysq-injection MFMA: A[m][k]=1 for k=0,1 (lanes<32), else 0.
    s16x8 aone;
#pragma unroll
    for (int j = 0; j < 8; ++j) aone[j] = 0;
    if (h == 0) { aone[0] = (short)0x3F80; aone[1] = (short)0x3F80; }

    f32x16 zero16;
#pragma unroll
    for (int r = 0; r < 16; ++r) zero16[r] = 0.f;

    // --- Prologue: chunk 0 -> buf0 (stride-16B per thread: conflict-free).
    const int4* gy = (const int4*)yfrag;
    int4 ra = gy[tid];
    int4 rb = gy[512 + tid];
    int4 rc = gy[1024 + tid];
    {
        int4* s = (int4*)s_buf;
        s[tid] = ra; s[512 + tid] = rb; s[1024 + tid] = rc;
    }

    uint32_t best[16], second[16];
#pragma unroll
    for (int r = 0; r < 16; ++r) { best[r] = 0xFFFFFFFFu; second[r] = 0xFFFFFFFFu; }

    for (int ch = 0; ch < N_CHUNKS; ++ch) {
        // Prefetch next chunk into regs BEFORE the barrier (latency overlap).
        if (ch + 1 < N_CHUNKS) {
            const int base = (ch + 1) * 1536;
            ra = gy[base + tid];
            rb = gy[base + 512 + tid];
            rc = gy[base + 1024 + tid];
        }
        __syncthreads();   // buf[ch&1] writes (prev iter / prologue) visible

        const char* bb = s_buf + (ch & 1) * CHUNK_B + lane * 16;
#pragma unroll
        for (int t = 0; t < CHUNK_T; ++t) {
            const s16x8 byh = *(const s16x8*)(bb + t * TILE_B);          // conflict-free
            const s16x8 byl = *(const s16x8*)(bb + t * TILE_B + 1024);
            const s16x8 bys = *(const s16x8*)(bb + t * TILE_B + 2048);
            f32x16 acc = __builtin_amdgcn_mfma_f32_32x32x16_bf16(a1, byh, zero16, 0, 0, 0);
            acc = __builtin_amdgcn_mfma_f32_32x32x16_bf16(a2, byh, acc, 0, 0, 0);
            acc = __builtin_amdgcn_mfma_f32_32x32x16_bf16(a1, byl, acc, 0, 0, 0);
            acc = __builtin_amdgcn_mfma_f32_32x32x16_bf16(aone, bys, acc, 0, 0, 0);
            const uint32_t tcur = (uint32_t)(ch * CHUNK_T + t);
#pragma unroll
            for (int r = 0; r < 16; ++r) {
                const uint32_t kb = (__float_as_uint(acc[r]) & 0xFFFFFF00u) | tcur;
                const uint32_t ob = best[r];
                second[r] = umin32(second[r], umax32(ob, kb));
                best[r]   = umin32(ob, kb);
            }
        }
        // Write next chunk to the OTHER buffer (safe: its last readers were
        // fenced by this iteration's top barrier).
        if (ch + 1 < N_CHUNKS) {
            int4* s = (int4*)(s_buf + ((ch + 1) & 1) * CHUNK_B);
            s[tid] = ra; s[512 + tid] = rb; s[1024 + tid] = rc;
        }
    }

    // --- Reduce across the 32 columns. C/D: col=lane&31,
    // row=(r&3)+8*(r>>2)+4*h. Reuse s_buf: keys [wave*1024 + row*32 + col].
    __syncthreads();
    uint32_t* s_red = (uint32_t*)s_buf;            // 8*32*32 u32 = 32 KB
#pragma unroll
    for (int r = 0; r < 16; ++r) {
        const int row = (r & 3) + 8 * (r >> 2) + 4 * h;
        s_red[wave * 1024 + row * 32 + col] = best[r];
    }
    __syncthreads();

    uint32_t b1 = 0xFFFFFFFFu, b2 = 0xFFFFFFFFu;
    int cwin = 0;
    if (tid < 256) {
        const int w = tid >> 5, row = tid & 31;
#pragma unroll
        for (int c = 0; c < 32; ++c) {
            const uint32_t k = s_red[w * 1024 + row * 32 + c];
            cwin = (k < b1) ? c : cwin;         // strict <: earliest col on equal keys
            b2 = umin32(b2, umax32(b1, k));     // 2nd-min of bests
            b1 = umin32(b1, k);
        }
    }
    __syncthreads();
#pragma unroll
    for (int r = 0; r < 16; ++r) {
        const int row = (r & 3) + 8 * (r >> 2) + 4 * h;
        s_red[wave * 1024 + row * 32 + col] = second[r];
    }
    __syncthreads();

    if (tid < 256) {
        const int w = tid >> 5, row = tid & 31;
        uint32_t smin = 0xFFFFFFFFu;
#pragma unroll
        for (int c = 0; c < 32; ++c)
            smin = umin32(smin, s_red[w * 1024 + row * 32 + c]);
        const uint32_t secondAll = umin32(smin, b2);
        const float s1 = __uint_as_float(b1 & 0xFFFFFF00u);
        const float s2 = __uint_as_float(secondAll & 0xFFFFFF00u);
        const int n = (int)(b1 & 0xFFu) * 32 + cwin;
        const int m = blockIdx.x * 256 + tid;   // = rowBase(w) + row

        bool amb = (s2 - s1 <= TIE_EPS);
        if (amb) {
            const int pos = atomicAdd(cnt, 1);
            if (pos < list_cap) list[pos] = m;
            else amb = false;                   // overflow: keep screened winner
        }
        if (!amb) {
            const float* cc2 = colors + (size_t)n * 3;
            float* o = out + (size_t)m * 3;
            o[0] = cc2[0];
            o[1] = cc2[1];
            o[2] = cc2[2];
        }
    }
}

// ---------------------------------------------------------------------------
// Kernel 3 (rescan): one wave per ambiguous row, fp64 exact (= f64 numpy ref),
// 8192 waves so latency is hidden by TLP; unroll-2 for ILP within a wave.
// ---------------------------------------------------------------------------
__global__ __launch_bounds__(256) void rescan_kernel(
    const float* __restrict__ x_all,
    const float* __restrict__ colors,
    const float* __restrict__ verts,
    const int* __restrict__ cnt,
    const int* __restrict__ list,
    int list_cap,
    float* __restrict__ out)
{
    const int wavesPerBlock = blockDim.x >> 6;
    const int wid  = blockIdx.x * wavesPerBlock + (threadIdx.x >> 6);
    const int lane = threadIdx.x & 63;
    const int nWaves = gridDim.x * wavesPerBlock;

    int ccount = *cnt;
    if (ccount > list_cap) ccount = list_cap;

    for (int rr = wid; rr < ccount; rr += nWaves) {
        const int m = list[rr];
        double bx[D_DIM];
#pragma unroll
        for (int d = 0; d < D_DIM; ++d)
            bx[d] = (double)x_all[(size_t)m * D_DIM + d];

        double best = INFINITY;
        int bi = 0x7fffffff;
#pragma unroll 2
        for (int n = lane; n < N_VERTS; n += 64) {
            const float* y = verts + (size_t)n * D_DIM;
            double dot = 0.0, ys = 0.0;
#pragma unroll
            for (int d = 0; d < D_DIM; ++d) {
                const double yd = (double)y[d];
                dot = fma(bx[d], yd, dot);
                ys  = fma(yd, yd, ys);
            }
            const double s = ys - 2.0 * dot;
            if (s < best || (s == best && n < bi)) { best = s; bi = n; }
        }
#pragma unroll
        for (int off = 32; off > 0; off >>= 1) {
            const double ob = __shfl_xor(best, off, 64);
            const int    oi = __shfl_xor(bi, off, 64);
            if (ob < best || (ob == best && oi < bi)) { best = ob; bi = oi; }
        }
        if (lane == 0) {
            const float* cc = colors + (size_t)bi * 3;
            float* o = out + (size_t)m * 3;
            o[0] = cc[0];
            o[1] = cc[1];
            o[2] = cc[2];
        }
    }
}

// ---------------------------------------------------------------------------
extern "C" void kernel_launch(void* const* d_in, const int* in_sizes, int n_in,
                              void* d_out, int out_size, void* d_ws, size_t ws_size,
                              hipStream_t stream) {
    const float* cse_embedding       = (const float*)d_in[0]; // (M,16)
    const float* verts_colors        = (const float*)d_in[1]; // (N,3)
    const float* verts_cse_embedding = (const float*)d_in[2]; // (N,16)
    float* out = (float*)d_out;                               // (M,3)

    char* ws = (char*)d_ws;
    char*  yfrag = ws + WS_YFRAG_OFF;
    int*   cnt   = (int*)(ws + WS_CNT_OFF);
    int*   list  = (int*)(ws + WS_LIST_OFF);
    int list_cap = (int)((ws_size > WS_LIST_OFF)
                         ? ((ws_size - WS_LIST_OFF) / sizeof(int)) : 0);
    if (list_cap > M_ROWS) list_cap = M_ROWS;

    pack_y_kernel<<<(N_TILES * 64) / 256, 256, 0, stream>>>(
        verts_cse_embedding, yfrag, cnt);

    mfma_screen_kernel<<<M_ROWS / 256, 512, 0, stream>>>(
        cse_embedding, verts_colors, yfrag, out, cnt, list, list_cap);

    rescan_kernel<<<2048, 256, 0, stream>>>(
        cse_embedding, verts_colors, verts_cse_embedding, cnt, list,
        list_cap, out);
}

// Round 2
// 209.837 us; speedup vs baseline: 2.6956x; 2.6956x over previous
//
#include <hip/hip_runtime.h>
#include <math.h>
#include <stdint.h>

// Problem: M=131072 rows, N=4000 verts (padded to 4096), D=16.
#define M_ROWS   131072
#define N_VERTS  4000
#define N_PAD    4096
#define D_DIM    16
#define N_TILES  (N_PAD / 32)          // 128 n-tiles of 32 verts
#define TILE_B   3072                  // per tile: yh 1KB | yl 1KB | ysf 1KB
#define CHUNK_T  8                     // tiles per LDS chunk
#define CHUNK_B  (CHUNK_T * TILE_B)    // 24576 B per chunk
#define N_CHUNKS (N_TILES / CHUNK_T)   // 16

// Scores are biased +128 so they are provably positive (score >= -||x||^2 and
// ||x||^2 < 128 for chi^2_16 data at astronomical confidence) -> positive-float
// bit pattern is monotone as u32 -> min_u32 does argmin via packed keys.
#define SCORE_BIAS 128.0f
// key = (score_bits & ~0xFF) | tile (tile 0..127 fits in 8 bits).
// Error budget: 8-bit mantissa truncation <= 7.8e-3 (score<256 for near-best),
// split-bf16 arithmetic ~1e-3, dropped al*yl cross term <= 4.9e-4,
// ys carried as bf16 hi+lo pair <= 7.3e-4.  TIE_EPS = 0.03 >= 2x total.
#define TIE_EPS 0.03f

// d_ws layout (bytes):
//   [0      .. 393216)  yfrag : N_TILES x 3072 B, fragment-ordered 32x32 data
//   [393216 .. 393220)  cnt
//   [393280 .. ...   )  list  : ambiguous row indices
#define WS_YFRAG_OFF 0
#define WS_CNT_OFF   393216
#define WS_LIST_OFF  393280

typedef float f32x16 __attribute__((ext_vector_type(16)));
typedef short s16x8  __attribute__((ext_vector_type(8)));

__device__ __forceinline__ unsigned short f32_to_bf16_rne(float f) {
    unsigned int u = __float_as_uint(f);
    u = (u + 0x7fffu + ((u >> 16) & 1u)) >> 16;
    return (unsigned short)u;
}
__device__ __forceinline__ float bf16_to_f32(unsigned short h) {
    return __uint_as_float(((unsigned int)h) << 16);
}
__device__ __forceinline__ uint32_t umin32(uint32_t a, uint32_t b) { return a < b ? a : b; }
__device__ __forceinline__ uint32_t umax32(uint32_t a, uint32_t b) { return a > b ? a : b; }

// ---------------------------------------------------------------------------
// Kernel 1: pack Y into 32x32-MFMA fragment order.
// B-operand layout for mfma_f32_32x32x16_bf16 (verified R1, absmax=0):
// B[n = lane&31][k = (lane>>5)*8 + j].
// Per tile T (32 verts): yh frag (64 lanes x 16B), yl frag, ysf frag.
// ysf holds (bias+||y||^2) as a bf16 hi/lo pair in k-slots 0,1 (lanes<32),
// consumed by an extra MFMA against a "ones" A-fragment -> acc init via MFMA.
// One thread per (tile, lane) = 8192 threads.
// ---------------------------------------------------------------------------
__global__ void pack_y_kernel(const float* __restrict__ verts,
                              char* __restrict__ yfrag,
                              int* __restrict__ cnt) {
    const int tid = blockIdx.x * blockDim.x + threadIdx.x;   // 0..8191
    if (tid == 0) *cnt = 0;

    const int T   = tid >> 6;
    const int l   = tid & 63;
    const int col = l & 31;
    const int h   = l >> 5;
    const int n   = T * 32 + col;
    const int d0  = h * 8;

    float v[8];
    if (n < N_VERTS) {
        const float* y = verts + (size_t)n * D_DIM + d0;
#pragma unroll
        for (int j = 0; j < 8; ++j) v[j] = y[j];
    } else {
#pragma unroll
        for (int j = 0; j < 8; ++j) v[j] = 0.f;
    }
    s16x8 fh, fl;
#pragma unroll
    for (int j = 0; j < 8; ++j) {
        const unsigned short hh = f32_to_bf16_rne(v[j]);
        fh[j] = (short)hh;
        fl[j] = (short)f32_to_bf16_rne(v[j] - bf16_to_f32(hh));
    }
    char* tb = yfrag + (size_t)T * TILE_B + (size_t)l * 16;
    *(s16x8*)(tb)        = fh;
    *(s16x8*)(tb + 1024) = fl;

    // ysf: k-slots 0,1 (lanes < 32) hold bf16 hi/lo of bias+||y||^2.
    s16x8 fy;
#pragma unroll
    for (int j = 0; j < 8; ++j) fy[j] = 0;
    if (h == 0) {
        float ys;
        if (n < N_VERTS) {
            ys = SCORE_BIAS;
            const float* y = verts + (size_t)n * D_DIM;
#pragma unroll
            for (int d = 0; d < D_DIM; ++d) ys = fmaf(y[d], y[d], ys);
        } else {
            ys = 1e30f;   // pad cols never win
        }
        const unsigned short ysh = f32_to_bf16_rne(ys);
        fy[0] = (short)ysh;
        fy[1] = (short)f32_to_bf16_rne(ys - bf16_to_f32(ysh));
    }
    *(s16x8*)(tb + 2048) = fy;
}

// ---------------------------------------------------------------------------
// Kernel 2 (MFMA screen, 32x32x16): 512 thr = 8 waves, wave = 32 rows x all n.
// Per tile: acc = ah*yh + al*yh + ah*yl + ones*ysf  (4 chained MFMAs,
// persistent zero16 C-operand, no per-tile acc-init movs).
// Key = (bits & ~0xFF) | tile -> min_u32 tracks best+argmin, max/min second.
// Double-buffered 24KB LDS chunks, ONE barrier per chunk (reg-prefetch).
// Grid = 512 blocks: all co-resident at 2 blocks/CU (48KB LDS) -> zero tail.
//
// R2 fix: `#pragma unroll 1` on the tile loop. Full unroll (R1) pipelined
// 8x (16-reg acc + 12-reg B-frags) = ~224 transient VGPRs -> scratch spill
// (2.2 GB/dispatch of scratch traffic, 455 us). Rolled loop keeps peak
// pressure ~114 < 128 cap; cross-tile latency hiding comes from the 4
// resident waves/SIMD, not intra-wave pipelining.
// ---------------------------------------------------------------------------
__global__ __launch_bounds__(512, 4) void mfma_screen_kernel(
    const float* __restrict__ x_all,    // (M,16)
    const float* __restrict__ colors,   // (N,3)
    const char* __restrict__ yfrag,     // N_TILES x 3072 B
    float* __restrict__ out,            // (M,3)
    int* __restrict__ cnt,
    int* __restrict__ list,
    int list_cap)
{
    __shared__ __align__(16) char s_buf[2 * CHUNK_B];   // 48 KB (reused for reduce)

    const int tid  = threadIdx.x;
    const int wave = tid >> 6;
    const int lane = tid & 63;
    const int col  = lane & 31;          // A row / B col / C-D col
    const int h    = lane >> 5;          // k-half select
    const int rowBase = blockIdx.x * 256 + wave * 32;

    // --- A fragments (built once). Lane supplies A[m=col][k=h*8+j].
    const float* xr = x_all + (size_t)(rowBase + col) * D_DIM + h * 8;
    const float4 xa = *(const float4*)xr;
    const float4 xb = *(const float4*)(xr + 4);
    const float xv[8] = {xa.x, xa.y, xa.z, xa.w, xb.x, xb.y, xb.z, xb.w};
    s16x8 a1, a2;
#pragma unroll
    for (int j = 0; j < 8; ++j) {
        const float a = -2.0f * xv[j];
        const unsigned short hh = f32_to_bf16_rne(a);
        a1[j] = (short)hh;
        a2[j] = (short)f32_to_bf16_rne(a - bf16_to_f32(hh));
    }
    // ones-A for the ysq-injection MFMA: A[m][k]=1 for k=0,1 (lanes<32), else 0.
    s16x8 aone;
#pragma unroll
    for (int j = 0; j < 8; ++j) aone[j] = 0;
    if (h == 0) { aone[0] = (short)0x3F80; aone[1] = (short)0x3F80; }

    f32x16 zero16;
#pragma unroll
    for (int r = 0; r < 16; ++r) zero16[r] = 0.f;

    // --- Prologue: chunk 0 -> buf0 (stride-16B per thread: conflict-free).
    const int4* gy = (const int4*)yfrag;
    int4 ra = gy[tid];
    int4 rb = gy[512 + tid];
    int4 rc = gy[1024 + tid];
    {
        int4* s = (int4*)s_buf;
        s[tid] = ra; s[512 + tid] = rb; s[1024 + tid] = rc;
    }

    uint32_t best[16], second[16];
#pragma unroll
    for (int r = 0; r < 16; ++r) { best[r] = 0xFFFFFFFFu; second[r] = 0xFFFFFFFFu; }

    for (int ch = 0; ch < N_CHUNKS; ++ch) {
        // Prefetch next chunk into regs BEFORE the barrier (latency overlap).
        if (ch + 1 < N_CHUNKS) {
            const int base = (ch + 1) * 1536;
            ra = gy[base + tid];
            rb = gy[base + 512 + tid];
            rc = gy[base + 1024 + tid];
        }
        __syncthreads();   // buf[ch&1] writes (prev iter / prologue) visible

        const char* bb = s_buf + (ch & 1) * CHUNK_B + lane * 16;
#pragma unroll 1
        for (int t = 0; t < CHUNK_T; ++t) {
            const s16x8 byh = *(const s16x8*)(bb + t * TILE_B);          // conflict-free
            const s16x8 byl = *(const s16x8*)(bb + t * TILE_B + 1024);
            const s16x8 bys = *(const s16x8*)(bb + t * TILE_B + 2048);
            f32x16 acc = __builtin_amdgcn_mfma_f32_32x32x16_bf16(a1, byh, zero16, 0, 0, 0);
            acc = __builtin_amdgcn_mfma_f32_32x32x16_bf16(a2, byh, acc, 0, 0, 0);
            acc = __builtin_amdgcn_mfma_f32_32x32x16_bf16(a1, byl, acc, 0, 0, 0);
            acc = __builtin_amdgcn_mfma_f32_32x32x16_bf16(aone, bys, acc, 0, 0, 0);
            const uint32_t tcur = (uint32_t)(ch * CHUNK_T + t);
#pragma unroll
            for (int r = 0; r < 16; ++r) {
                const uint32_t kb = (__float_as_uint(acc[r]) & 0xFFFFFF00u) | tcur;
                const uint32_t ob = best[r];
                second[r] = umin32(second[r], umax32(ob, kb));
                best[r]   = umin32(ob, kb);
            }
        }
        // Write next chunk to the OTHER buffer (safe: its last readers were
        // fenced by this iteration's top barrier).
        if (ch + 1 < N_CHUNKS) {
            int4* s = (int4*)(s_buf + ((ch + 1) & 1) * CHUNK_B);
            s[tid] = ra; s[512 + tid] = rb; s[1024 + tid] = rc;
        }
    }

    // --- Reduce across the 32 columns. C/D: col=lane&31,
    // row=(r&3)+8*(r>>2)+4*h. Reuse s_buf: keys [wave*1024 + row*32 + col].
    __syncthreads();
    uint32_t* s_red = (uint32_t*)s_buf;            // 8*32*32 u32 = 32 KB
#pragma unroll
    for (int r = 0; r < 16; ++r) {
        const int row = (r & 3) + 8 * (r >> 2) + 4 * h;
        s_red[wave * 1024 + row * 32 + col] = best[r];
    }
    __syncthreads();

    uint32_t b1 = 0xFFFFFFFFu, b2 = 0xFFFFFFFFu;
    int cwin = 0;
    if (tid < 256) {
        const int w = tid >> 5, row = tid & 31;
#pragma unroll
        for (int c = 0; c < 32; ++c) {
            const uint32_t k = s_red[w * 1024 + row * 32 + c];
            cwin = (k < b1) ? c : cwin;         // strict <: earliest col on equal keys
            b2 = umin32(b2, umax32(b1, k));     // 2nd-min of bests
            b1 = umin32(b1, k);
        }
    }
    __syncthreads();
#pragma unroll
    for (int r = 0; r < 16; ++r) {
        const int row = (r & 3) + 8 * (r >> 2) + 4 * h;
        s_red[wave * 1024 + row * 32 + col] = second[r];
    }
    __syncthreads();

    if (tid < 256) {
        const int w = tid >> 5, row = tid & 31;
        uint32_t smin = 0xFFFFFFFFu;
#pragma unroll
        for (int c = 0; c < 32; ++c)
            smin = umin32(smin, s_red[w * 1024 + row * 32 + c]);
        const uint32_t secondAll = umin32(smin, b2);
        const float s1 = __uint_as_float(b1 & 0xFFFFFF00u);
        const float s2 = __uint_as_float(secondAll & 0xFFFFFF00u);
        const int n = (int)(b1 & 0xFFu) * 32 + cwin;
        const int m = blockIdx.x * 256 + tid;   // = rowBase(w) + row

        bool amb = (s2 - s1 <= TIE_EPS);
        if (amb) {
            const int pos = atomicAdd(cnt, 1);
            if (pos < list_cap) list[pos] = m;
            else amb = false;                   // overflow: keep screened winner
        }
        if (!amb) {
            const float* cc2 = colors + (size_t)n * 3;
            float* o = out + (size_t)m * 3;
            o[0] = cc2[0];
            o[1] = cc2[1];
            o[2] = cc2[2];
        }
    }
}

// ---------------------------------------------------------------------------
// Kernel 3 (rescan): one wave per ambiguous row, fp64 exact (= f64 numpy ref),
// 8192 waves so latency is hidden by TLP; unroll-2 for ILP within a wave.
// ---------------------------------------------------------------------------
__global__ __launch_bounds__(256) void rescan_kernel(
    const float* __restrict__ x_all,
    const float* __restrict__ colors,
    const float* __restrict__ verts,
    const int* __restrict__ cnt,
    const int* __restrict__ list,
    int list_cap,
    float* __restrict__ out)
{
    const int wavesPerBlock = blockDim.x >> 6;
    const int wid  = blockIdx.x * wavesPerBlock + (threadIdx.x >> 6);
    const int lane = threadIdx.x & 63;
    const int nWaves = gridDim.x * wavesPerBlock;

    int ccount = *cnt;
    if (ccount > list_cap) ccount = list_cap;

    for (int rr = wid; rr < ccount; rr += nWaves) {
        const int m = list[rr];
        double bx[D_DIM];
#pragma unroll
        for (int d = 0; d < D_DIM; ++d)
            bx[d] = (double)x_all[(size_t)m * D_DIM + d];

        double best = INFINITY;
        int bi = 0x7fffffff;
#pragma unroll 2
        for (int n = lane; n < N_VERTS; n += 64) {
            const float* y = verts + (size_t)n * D_DIM;
            double dot = 0.0, ys = 0.0;
#pragma unroll
            for (int d = 0; d < D_DIM; ++d) {
                const double yd = (double)y[d];
                dot = fma(bx[d], yd, dot);
                ys  = fma(yd, yd, ys);
            }
            const double s = ys - 2.0 * dot;
            if (s < best || (s == best && n < bi)) { best = s; bi = n; }
        }
#pragma unroll
        for (int off = 32; off > 0; off >>= 1) {
            const double ob = __shfl_xor(best, off, 64);
            const int    oi = __shfl_xor(bi, off, 64);
            if (ob < best || (ob == best && oi < bi)) { best = ob; bi = oi; }
        }
        if (lane == 0) {
            const float* cc = colors + (size_t)bi * 3;
            float* o = out + (size_t)m * 3;
            o[0] = cc[0];
            o[1] = cc[1];
            o[2] = cc[2];
        }
    }
}

// ---------------------------------------------------------------------------
extern "C" void kernel_launch(void* const* d_in, const int* in_sizes, int n_in,
                              void* d_out, int out_size, void* d_ws, size_t ws_size,
                              hipStream_t stream) {
    const float* cse_embedding       = (const float*)d_in[0]; // (M,16)
    const float* verts_colors        = (const float*)d_in[1]; // (N,3)
    const float* verts_cse_embedding = (const float*)d_in[2]; // (N,16)
    float* out = (float*)d_out;                               // (M,3)

    char* ws = (char*)d_ws;
    char*  yfrag = ws + WS_YFRAG_OFF;
    int*   cnt   = (int*)(ws + WS_CNT_OFF);
    int*   list  = (int*)(ws + WS_LIST_OFF);
    int list_cap = (int)((ws_size > WS_LIST_OFF)
                         ? ((ws_size - WS_LIST_OFF) / sizeof(int)) : 0);
    if (list_cap > M_ROWS) list_cap = M_ROWS;

    pack_y_kernel<<<(N_TILES * 64) / 256, 256, 0, stream>>>(
        verts_cse_embedding, yfrag, cnt);

    mfma_screen_kernel<<<M_ROWS / 256, 512, 0, stream>>>(
        cse_embedding, verts_colors, yfrag, out, cnt, list, list_cap);

    rescan_kernel<<<2048, 256, 0, stream>>>(
        cse_embedding, verts_colors, verts_cse_embedding, cnt, list,
        list_cap, out);
}

// Round 4
// 198.340 us; speedup vs baseline: 2.8519x; 1.0580x over previous
//
#include <hip/hip_runtime.h>
#include <math.h>
#include <stdint.h>

// Problem: M=131072 rows, N=4000 verts (padded to 4096), D=16.
#define M_ROWS   131072
#define N_VERTS  4000
#define N_PAD    4096
#define D_DIM    16
#define N_TILES  (N_PAD / 32)          // 128 n-tiles of 32 verts
#define TILE_B   3072                  // per tile: yh 1KB | yl 1KB | ysf 1KB
#define CHUNK_T  8                     // tiles per LDS chunk
#define CHUNK_B  (CHUNK_T * TILE_B)    // 24576 B per chunk
#define N_CHUNKS (N_TILES / CHUNK_T)   // 16

// Scores are biased +128 so they are provably positive (score >= -||x||^2 and
// ||x||^2 < 128 for chi^2_16 data at astronomical confidence) -> positive-float
// bit pattern is monotone as u32 -> min_u32 does argmin via packed keys.
#define SCORE_BIAS 128.0f
// key = (score_bits & ~0xFF) | tile (tile 0..127 fits in 8 bits).
// Error budget: 8-bit mantissa truncation <= 7.8e-3 (score<256 for near-best),
// split-bf16 arithmetic ~1e-3, dropped al*yl cross term <= 4.9e-4,
// ys carried as bf16 hi+lo pair <= 7.3e-4.  TIE_EPS = 0.03 >= 2x total.
#define TIE_EPS 0.03f

// d_ws layout (bytes):
//   [0      .. 393216)  yfrag : N_TILES x 3072 B, fragment-ordered 32x32 data
//   [393216 .. 393220)  cnt
//   [393280 .. ...   )  list  : ambiguous row indices
#define WS_YFRAG_OFF 0
#define WS_CNT_OFF   393216
#define WS_LIST_OFF  393280

typedef float f32x16 __attribute__((ext_vector_type(16)));
typedef short s16x8  __attribute__((ext_vector_type(8)));

__device__ __forceinline__ unsigned short f32_to_bf16_rne(float f) {
    unsigned int u = __float_as_uint(f);
    u = (u + 0x7fffu + ((u >> 16) & 1u)) >> 16;
    return (unsigned short)u;
}
__device__ __forceinline__ float bf16_to_f32(unsigned short h) {
    return __uint_as_float(((unsigned int)h) << 16);
}
__device__ __forceinline__ uint32_t umin32(uint32_t a, uint32_t b) { return a < b ? a : b; }
__device__ __forceinline__ uint32_t umax32(uint32_t a, uint32_t b) { return a > b ? a : b; }

// median(a,b,c) in one VALU op. Under the invariant a <= c this equals
// min(c, max(a, b)) -- the second-best update. LLVM can't derive this
// (only valid under the invariant), so force v_med3_u32 via asm.
// Case check (b=new key kb): kb<a -> a; a<=kb<=c -> kb; kb>c -> c.  All match.
// Invariant preserved: min(a,kb) <= min(c, max(a,kb)).
__device__ __forceinline__ uint32_t med3_u32(uint32_t a, uint32_t b, uint32_t c) {
    uint32_t d;
    asm("v_med3_u32 %0, %1, %2, %3" : "=v"(d) : "v"(a), "v"(b), "v"(c));
    return d;
}

// ---------------------------------------------------------------------------
// Kernel 1: pack Y into 32x32-MFMA fragment order.
// B-operand layout for mfma_f32_32x32x16_bf16 (verified R1/R2, absmax=0):
// B[n = lane&31][k = (lane>>5)*8 + j].
// Per tile T (32 verts): yh frag (64 lanes x 16B), yl frag, ysf frag.
// ysf holds (bias+||y||^2) as a bf16 hi/lo pair in k-slots 0,1 (lanes<32),
// consumed by an extra MFMA against a "ones" A-fragment -> acc init via MFMA.
// One thread per (tile, lane) = 8192 threads.
// ---------------------------------------------------------------------------
__global__ void pack_y_kernel(const float* __restrict__ verts,
                              char* __restrict__ yfrag,
                              int* __restrict__ cnt) {
    const int tid = blockIdx.x * blockDim.x + threadIdx.x;   // 0..8191
    if (tid == 0) *cnt = 0;

    const int T   = tid >> 6;
    const int l   = tid & 63;
    const int col = l & 31;
    const int h   = l >> 5;
    const int n   = T * 32 + col;
    const int d0  = h * 8;

    float v[8];
    if (n < N_VERTS) {
        const float* y = verts + (size_t)n * D_DIM + d0;
#pragma unroll
        for (int j = 0; j < 8; ++j) v[j] = y[j];
    } else {
#pragma unroll
        for (int j = 0; j < 8; ++j) v[j] = 0.f;
    }
    s16x8 fh, fl;
#pragma unroll
    for (int j = 0; j < 8; ++j) {
        const unsigned short hh = f32_to_bf16_rne(v[j]);
        fh[j] = (short)hh;
        fl[j] = (short)f32_to_bf16_rne(v[j] - bf16_to_f32(hh));
    }
    char* tb = yfrag + (size_t)T * TILE_B + (size_t)l * 16;
    *(s16x8*)(tb)        = fh;
    *(s16x8*)(tb + 1024) = fl;

    // ysf: k-slots 0,1 (lanes < 32) hold bf16 hi/lo of bias+||y||^2.
    s16x8 fy;
#pragma unroll
    for (int j = 0; j < 8; ++j) fy[j] = 0;
    if (h == 0) {
        float ys;
        if (n < N_VERTS) {
            ys = SCORE_BIAS;
            const float* y = verts + (size_t)n * D_DIM;
#pragma unroll
            for (int d = 0; d < D_DIM; ++d) ys = fmaf(y[d], y[d], ys);
        } else {
            ys = 1e30f;   // pad cols never win
        }
        const unsigned short ysh = f32_to_bf16_rne(ys);
        fy[0] = (short)ysh;
        fy[1] = (short)f32_to_bf16_rne(ys - bf16_to_f32(ysh));
    }
    *(s16x8*)(tb + 2048) = fy;
}

// ---------------------------------------------------------------------------
// Kernel 2 (MFMA screen, 32x32x16): 512 thr = 8 waves, wave = 32 rows x all n.
// Per tile: acc = ah*yh + al*yh + ah*yl + ones*ysf  (4 chained MFMAs,
// persistent zero16 C-operand, no per-tile acc-init movs).
// Key = (bits & ~0xFF) | tile -> min_u32 best+argmin, v_med3_u32 second.
// Double-buffered 24KB LDS chunks, ONE barrier per chunk, REG prefetch
// (global loads issued before the barrier, LDS writes after the compute
// loop -- T14 split). NOTE R3 post-mortem: replacing this with
// global_load_lds DMA staging FAILED correctness (absmax 0.97) -- do not
// retry without an isolated A/B; reg staging is the verified path.
// Grid = 512 blocks: all co-resident at 2 blocks/CU (48KB LDS) -> zero tail.
// `#pragma unroll 1`: full unroll pipelines 8x(acc16+frag12) -> spill (R1).
// ---------------------------------------------------------------------------
__global__ __launch_bounds__(512, 4) void mfma_screen_kernel(
    const float* __restrict__ x_all,    // (M,16)
    const float* __restrict__ colors,   // (N,3)
    const char* __restrict__ yfrag,     // N_TILES x 3072 B
    float* __restrict__ out,            // (M,3)
    int* __restrict__ cnt,
    int* __restrict__ list,
    int list_cap)
{
    __shared__ __align__(16) char s_buf[2 * CHUNK_B];   // 48 KB (reused for reduce)

    const int tid  = threadIdx.x;
    const int wave = tid >> 6;
    const int lane = tid & 63;
    const int col  = lane & 31;          // A row / B col / C-D col
    const int h    = lane >> 5;          // k-half select
    const int rowBase = blockIdx.x * 256 + wave * 32;

    // --- A fragments (built once). Lane supplies A[m=col][k=h*8+j].
    const float* xr = x_all + (size_t)(rowBase + col) * D_DIM + h * 8;
    const float4 xa = *(const float4*)xr;
    const float4 xb = *(const float4*)(xr + 4);
    const float xv[8] = {xa.x, xa.y, xa.z, xa.w, xb.x, xb.y, xb.z, xb.w};
    s16x8 a1, a2;
#pragma unroll
    for (int j = 0; j < 8; ++j) {
        const float a = -2.0f * xv[j];
        const unsigned short hh = f32_to_bf16_rne(a);
        a1[j] = (short)hh;
        a2[j] = (short)f32_to_bf16_rne(a - bf16_to_f32(hh));
    }
    // ones-A for the ysq-injection MFMA: A[m][k]=1 for k=0,1 (lanes<32), else 0.
    s16x8 aone;
#pragma unroll
    for (int j = 0; j < 8; ++j) aone[j] = 0;
    if (h == 0) { aone[0] = (short)0x3F80; aone[1] = (short)0x3F80; }

    f32x16 zero16;
#pragma unroll
    for (int r = 0; r < 16; ++r) zero16[r] = 0.f;

    // --- Prologue: chunk 0 -> buf0 (stride-16B per thread: conflict-free).
    const int4* gy = (const int4*)yfrag;
    int4 ra = gy[tid];
    int4 rb = gy[512 + tid];
    int4 rc = gy[1024 + tid];
    {
        int4* s = (int4*)s_buf;
        s[tid] = ra; s[512 + tid] = rb; s[1024 + tid] = rc;
    }

    uint32_t best[16], second[16];
#pragma unroll
    for (int r = 0; r < 16; ++r) { best[r] = 0xFFFFFFFFu; second[r] = 0xFFFFFFFFu; }

    for (int ch = 0; ch < N_CHUNKS; ++ch) {
        // Prefetch next chunk into regs BEFORE the barrier (latency overlap).
        if (ch + 1 < N_CHUNKS) {
            const int base = (ch + 1) * 1536;
            ra = gy[base + tid];
            rb = gy[base + 512 + tid];
            rc = gy[base + 1024 + tid];
        }
        __syncthreads();   // buf[ch&1] writes (prev iter / prologue) visible

        const char* bb = s_buf + (ch & 1) * CHUNK_B + lane * 16;
#pragma unroll 1
        for (int t = 0; t < CHUNK_T; ++t) {
            const s16x8 byh = *(const s16x8*)(bb + t * TILE_B);          // conflict-free
            const s16x8 byl = *(const s16x8*)(bb + t * TILE_B + 1024);
            const s16x8 bys = *(const s16x8*)(bb + t * TILE_B + 2048);
            f32x16 acc = __builtin_amdgcn_mfma_f32_32x32x16_bf16(a1, byh, zero16, 0, 0, 0);
            acc = __builtin_amdgcn_mfma_f32_32x32x16_bf16(a2, byh, acc, 0, 0, 0);
            acc = __builtin_amdgcn_mfma_f32_32x32x16_bf16(a1, byl, acc, 0, 0, 0);
            acc = __builtin_amdgcn_mfma_f32_32x32x16_bf16(aone, bys, acc, 0, 0, 0);
            const uint32_t tcur = (uint32_t)(ch * CHUNK_T + t);
#pragma unroll
            for (int r = 0; r < 16; ++r) {
                const uint32_t kb = (__float_as_uint(acc[r]) & 0xFFFFFF00u) | tcur;
                second[r] = med3_u32(best[r], kb, second[r]);  // = min(sec, max(best,kb))
                best[r]   = umin32(best[r], kb);
            }
        }
        // Write next chunk to the OTHER buffer (safe: its last readers were
        // fenced by this iteration's top barrier).
        if (ch + 1 < N_CHUNKS) {
            int4* s = (int4*)(s_buf + ((ch + 1) & 1) * CHUNK_B);
            s[tid] = ra; s[512 + tid] = rb; s[1024 + tid] = rc;
        }
    }

    // --- Reduce across the 32 columns. C/D: col=lane&31,
    // row=(r&3)+8*(r>>2)+4*h. Reuse s_buf: keys [wave*1024 + row*32 + col].
    __syncthreads();
    uint32_t* s_red = (uint32_t*)s_buf;            // 8*32*32 u32 = 32 KB
#pragma unroll
    for (int r = 0; r < 16; ++r) {
        const int row = (r & 3) + 8 * (r >> 2) + 4 * h;
        s_red[wave * 1024 + row * 32 + col] = best[r];
    }
    __syncthreads();

    uint32_t b1 = 0xFFFFFFFFu, b2 = 0xFFFFFFFFu;
    int cwin = 0;
    if (tid < 256) {
        const int w = tid >> 5, row = tid & 31;
#pragma unroll
        for (int c = 0; c < 32; ++c) {
            const uint32_t k = s_red[w * 1024 + row * 32 + c];
            cwin = (k < b1) ? c : cwin;         // strict <: earliest col on equal keys
            b2 = umin32(b2, umax32(b1, k));     // 2nd-min of bests
            b1 = umin32(b1, k);
        }
    }
    __syncthreads();
#pragma unroll
    for (int r = 0; r < 16; ++r) {
        const int row = (r & 3) + 8 * (r >> 2) + 4 * h;
        s_red[wave * 1024 + row * 32 + col] = second[r];
    }
    __syncthreads();

    if (tid < 256) {
        const int w = tid >> 5, row = tid & 31;
        uint32_t smin = 0xFFFFFFFFu;
#pragma unroll
        for (int c = 0; c < 32; ++c)
            smin = umin32(smin, s_red[w * 1024 + row * 32 + c]);
        const uint32_t secondAll = umin32(smin, b2);
        const float s1 = __uint_as_float(b1 & 0xFFFFFF00u);
        const float s2 = __uint_as_float(secondAll & 0xFFFFFF00u);
        const int n = (int)(b1 & 0xFFu) * 32 + cwin;
        const int m = blockIdx.x * 256 + tid;   // = rowBase(w) + row

        bool amb = (s2 - s1 <= TIE_EPS);
        if (amb) {
            const int pos = atomicAdd(cnt, 1);
            if (pos < list_cap) list[pos] = m;
            else amb = false;                   // overflow: keep screened winner
        }
        if (!amb) {
            const float* cc2 = colors + (size_t)n * 3;
            float* o = out + (size_t)m * 3;
            o[0] = cc2[0];
            o[1] = cc2[1];
            o[2] = cc2[2];
        }
    }
}

// ---------------------------------------------------------------------------
// Kernel 3 (rescan): one wave per ambiguous row, fp64 exact (= f64 numpy ref),
// 8192 waves so latency is hidden by TLP; unroll-2 for ILP within a wave.
// ---------------------------------------------------------------------------
__global__ __launch_bounds__(256) void rescan_kernel(
    const float* __restrict__ x_all,
    const float* __restrict__ colors,
    const float* __restrict__ verts,
    const int* __restrict__ cnt,
    const int* __restrict__ list,
    int list_cap,
    float* __restrict__ out)
{
    const int wavesPerBlock = blockDim.x >> 6;
    const int wid  = blockIdx.x * wavesPerBlock + (threadIdx.x >> 6);
    const int lane = threadIdx.x & 63;
    const int nWaves = gridDim.x * wavesPerBlock;

    int ccount = *cnt;
    if (ccount > list_cap) ccount = list_cap;

    for (int rr = wid; rr < ccount; rr += nWaves) {
        const int m = list[rr];
        double bx[D_DIM];
#pragma unroll
        for (int d = 0; d < D_DIM; ++d)
            bx[d] = (double)x_all[(size_t)m * D_DIM + d];

        double best = INFINITY;
        int bi = 0x7fffffff;
#pragma unroll 2
        for (int n = lane; n < N_VERTS; n += 64) {
            const float* y = verts + (size_t)n * D_DIM;
            double dot = 0.0, ys = 0.0;
#pragma unroll
            for (int d = 0; d < D_DIM; ++d) {
                const double yd = (double)y[d];
                dot = fma(bx[d], yd, dot);
                ys  = fma(yd, yd, ys);
            }
            const double s = ys - 2.0 * dot;
            if (s < best || (s == best && n < bi)) { best = s; bi = n; }
        }
#pragma unroll
        for (int off = 32; off > 0; off >>= 1) {
            const double ob = __shfl_xor(best, off, 64);
            const int    oi = __shfl_xor(bi, off, 64);
            if (ob < best || (ob == best && oi < bi)) { best = ob; bi = oi; }
        }
        if (lane == 0) {
            const float* cc = colors + (size_t)bi * 3;
            float* o = out + (size_t)m * 3;
            o[0] = cc[0];
            o[1] = cc[1];
            o[2] = cc[2];
        }
    }
}

// ---------------------------------------------------------------------------
extern "C" void kernel_launch(void* const* d_in, const int* in_sizes, int n_in,
                              void* d_out, int out_size, void* d_ws, size_t ws_size,
                              hipStream_t stream) {
    const float* cse_embedding       = (const float*)d_in[0]; // (M,16)
    const float* verts_colors        = (const float*)d_in[1]; // (N,3)
    const float* verts_cse_embedding = (const float*)d_in[2]; // (N,16)
    float* out = (float*)d_out;                               // (M,3)

    char* ws = (char*)d_ws;
    char*  yfrag = ws + WS_YFRAG_OFF;
    int*   cnt   = (int*)(ws + WS_CNT_OFF);
    int*   list  = (int*)(ws + WS_LIST_OFF);
    int list_cap = (int)((ws_size > WS_LIST_OFF)
                         ? ((ws_size - WS_LIST_OFF) / sizeof(int)) : 0);
    if (list_cap > M_ROWS) list_cap = M_ROWS;

    pack_y_kernel<<<(N_TILES * 64) / 256, 256, 0, stream>>>(
        verts_cse_embedding, yfrag, cnt);

    mfma_screen_kernel<<<M_ROWS / 256, 512, 0, stream>>>(
        cse_embedding, verts_colors, yfrag, out, cnt, list, list_cap);

    rescan_kernel<<<2048, 256, 0, stream>>>(
        cse_embedding, verts_colors, verts_cse_embedding, cnt, list,
        list_cap, out);
}